// Round 1
// baseline (67.397 us; speedup 1.0000x reference)
//
#include <hip/hip_runtime.h>

#define N_NODES 16384
#define N_EDGES 262144
#define DIM 256

// ---------------------------------------------------------------------------
// ws layout:
//   [0, 64KB)            uint deg[N_NODES]
//   [64KB, 64KB+4)       uint count (active edges)
//   [64KB+256, +2MB)     int2 active_edges[N_EDGES]  (worst case)
//   [aligned 256, +16MB) float h[N_NODES*DIM]        (if ws large enough)
// ---------------------------------------------------------------------------

__global__ void k_init(unsigned* __restrict__ deg, unsigned* __restrict__ count) {
    int i = blockIdx.x * blockDim.x + threadIdx.x;
    if (i < N_NODES) deg[i] = 1u;       // self-loop weight
    if (i == 0) *count = 0u;
}

__global__ void k_edges(const int* __restrict__ ei, const int* __restrict__ sec,
                        unsigned* __restrict__ deg, unsigned* __restrict__ count,
                        int2* __restrict__ list) {
    int e = blockIdx.x * blockDim.x + threadIdx.x;
    if (e >= N_EDGES) return;
    int r = ei[e];             // edge_index[0][e]  (message source)
    int c = ei[N_EDGES + e];   // edge_index[1][e]  (message target)
    if (sec[r] == sec[c]) {
        atomicAdd(&deg[c], 1u);
        unsigned pos = atomicAdd(count, 1u);
        list[pos] = make_int2(r, c);
    }
}

// h = x @ W; out = h * (1/deg) + b   (self-loop contribution fused)
// 64x64 tile, BK=32, 256 threads, 4x4 micro-tile per thread.
template <bool STORE_H>
__global__ __launch_bounds__(256) void k_gemm(
        const float* __restrict__ x, const float* __restrict__ W,
        const float* __restrict__ b, const unsigned* __restrict__ deg,
        float* __restrict__ h, float* __restrict__ out) {
    __shared__ float As[32][68];   // As[k][m], +4 pad
    __shared__ float Bs[32][68];   // Bs[k][n], +4 pad

    const int bm = blockIdx.y * 64;
    const int bn = blockIdx.x * 64;
    const int t  = threadIdx.x;
    const int tx = t & 15;         // n direction
    const int ty = t >> 4;         // m direction

    float acc[4][4] = {};

    for (int k0 = 0; k0 < DIM; k0 += 32) {
        // load x tile (64 rows x 32 cols), 2 float4 per thread, transpose into LDS
        #pragma unroll
        for (int i = 0; i < 2; ++i) {
            int idx = t + i * 256;            // 0..511
            int m = idx >> 3;                 // 0..63
            int k = (idx & 7) * 4;            // 0..28
            float4 v = *reinterpret_cast<const float4*>(&x[(size_t)(bm + m) * DIM + k0 + k]);
            As[k + 0][m] = v.x; As[k + 1][m] = v.y;
            As[k + 2][m] = v.z; As[k + 3][m] = v.w;
        }
        // load W tile (32 rows x 64 cols), 2 float4 per thread
        #pragma unroll
        for (int i = 0; i < 2; ++i) {
            int idx = t + i * 256;            // 0..511
            int k = idx >> 4;                 // 0..31
            int n = (idx & 15) * 4;
            *reinterpret_cast<float4*>(&Bs[k][n]) =
                *reinterpret_cast<const float4*>(&W[(size_t)(k0 + k) * DIM + bn + n]);
        }
        __syncthreads();
        #pragma unroll
        for (int kk = 0; kk < 32; ++kk) {
            float4 a  = *reinterpret_cast<const float4*>(&As[kk][ty * 4]);
            float4 bv = *reinterpret_cast<const float4*>(&Bs[kk][tx * 4]);
            float av[4] = {a.x, a.y, a.z, a.w};
            float bw[4] = {bv.x, bv.y, bv.z, bv.w};
            #pragma unroll
            for (int i = 0; i < 4; ++i)
                #pragma unroll
                for (int j = 0; j < 4; ++j)
                    acc[i][j] += av[i] * bw[j];
        }
        __syncthreads();
    }

    #pragma unroll
    for (int i = 0; i < 4; ++i) {
        int m = bm + ty * 4 + i;
        float sn = 1.0f / (float)deg[m];      // dinv[m]^2 (deg >= 1 always)
        #pragma unroll
        for (int j = 0; j < 4; ++j) {
            int n = bn + tx * 4 + j;
            float hv = acc[i][j];
            if (STORE_H) h[(size_t)m * DIM + n] = hv;
            out[(size_t)m * DIM + n] = hv * sn + b[n];
        }
    }
}

// one wave per active edge; lane l handles dims [4l, 4l+4)
__global__ void k_scatter(const float* __restrict__ h, const unsigned* __restrict__ deg,
                          const unsigned* __restrict__ count, const int2* __restrict__ list,
                          float* __restrict__ out) {
    unsigned nact = *count;
    unsigned wave   = (blockIdx.x * blockDim.x + threadIdx.x) >> 6;
    unsigned lane   = threadIdx.x & 63;
    unsigned nwaves = (gridDim.x * blockDim.x) >> 6;
    for (unsigned e = wave; e < nact; e += nwaves) {
        int2 rc = list[e];
        float norm = rsqrtf((float)deg[rc.x]) * rsqrtf((float)deg[rc.y]);
        float4 hv = *reinterpret_cast<const float4*>(&h[(size_t)rc.x * DIM + lane * 4]);
        float* o = &out[(size_t)rc.y * DIM + lane * 4];
        atomicAdd(o + 0, hv.x * norm);
        atomicAdd(o + 1, hv.y * norm);
        atomicAdd(o + 2, hv.z * norm);
        atomicAdd(o + 3, hv.w * norm);
    }
}

// fallback when ws can't hold h: recompute h[src] row on the fly (expected
// ~1.3K active edges, so this is cheap; W columns come from L2)
__global__ void k_scatter_recompute(const float* __restrict__ x, const float* __restrict__ W,
                                    const unsigned* __restrict__ deg,
                                    const unsigned* __restrict__ count,
                                    const int2* __restrict__ list,
                                    float* __restrict__ out) {
    __shared__ float xs[DIM];
    unsigned nact = *count;
    for (unsigned e = blockIdx.x; e < nact; e += gridDim.x) {
        int2 rc = list[e];
        __syncthreads();
        xs[threadIdx.x] = x[(size_t)rc.x * DIM + threadIdx.x];
        __syncthreads();
        float norm = rsqrtf((float)deg[rc.x]) * rsqrtf((float)deg[rc.y]);
        float a = 0.f;
        for (int k = 0; k < DIM; ++k) a += xs[k] * W[(size_t)k * DIM + threadIdx.x];
        atomicAdd(&out[(size_t)rc.y * DIM + threadIdx.x], a * norm);
    }
}

extern "C" void kernel_launch(void* const* d_in, const int* in_sizes, int n_in,
                              void* d_out, int out_size, void* d_ws, size_t ws_size,
                              hipStream_t stream) {
    const float* x  = (const float*)d_in[0];
    const float* W  = (const float*)d_in[1];
    const float* b  = (const float*)d_in[2];
    const int* ei   = (const int*)d_in[3];
    const int* sec  = (const int*)d_in[4];
    float* out      = (float*)d_out;

    char* ws = (char*)d_ws;
    unsigned* deg   = (unsigned*)ws;                         // 64 KB
    unsigned* count = (unsigned*)(ws + 65536);
    int2* list      = (int2*)(ws + 65536 + 256);
    size_t h_off = 65536 + 256 + (size_t)N_EDGES * sizeof(int2);
    h_off = (h_off + 255) & ~(size_t)255;
    float* h = (float*)(ws + h_off);
    const bool store_h = ws_size >= h_off + (size_t)N_NODES * DIM * sizeof(float);

    k_init<<<N_NODES / 256, 256, 0, stream>>>(deg, count);
    k_edges<<<N_EDGES / 256, 256, 0, stream>>>(ei, sec, deg, count, list);

    dim3 grid(DIM / 64, N_NODES / 64);
    if (store_h) {
        k_gemm<true><<<grid, 256, 0, stream>>>(x, W, b, deg, h, out);
        k_scatter<<<256, 256, 0, stream>>>(h, deg, count, list, out);
    } else {
        k_gemm<false><<<grid, 256, 0, stream>>>(x, W, b, deg, nullptr, out);
        k_scatter_recompute<<<512, 256, 0, stream>>>(x, W, deg, count, list, out);
    }
}

// Round 2
// 54.696 us; speedup vs baseline: 1.2322x; 1.2322x over previous
//
#include <hip/hip_runtime.h>
#include <hip/hip_bf16.h>

#define N_NODES 16384
#define N_EDGES 262144
#define DIM 256

typedef __attribute__((ext_vector_type(4))) float f32x4;
typedef __attribute__((ext_vector_type(8))) short bf16x8;

__device__ inline short f2bf(float f) {
    union { float f; unsigned u; } v; v.f = f;
    unsigned r = v.u + 0x7fffu + ((v.u >> 16) & 1u);   // round-to-nearest-even
    return (short)(r >> 16);
}

// ---------------------------------------------------------------------------
// ws layout:
//   [0, 64KB)                 uint deg[N_NODES]
//   [64KB, +4)                uint count
//   [64KB+256, +2MB)          int2 active_edges[N_EDGES]
//   [next 256-align, +128KB)  short Wt[DIM*DIM]   (bf16, transposed: Wt[n][k])
//   [next 256-align, +16MB)   float h[N_NODES*DIM]
// ---------------------------------------------------------------------------

__global__ void k_prep(const float* __restrict__ W, short* __restrict__ Wt,
                       unsigned* __restrict__ deg, unsigned* __restrict__ count) {
    int bid = blockIdx.x;
    int tid = threadIdx.x;
    if (bid < 256) {
        int idx = bid * 256 + tid;        // flat index into Wt
        int n = idx >> 8, k = idx & 255;
        Wt[idx] = f2bf(W[k * 256 + n]);   // Wt[n][k] = W[k][n]
    } else {
        int i = (bid - 256) * 256 + tid;
        deg[i] = 1u;                      // self-loop
        if (i == 0) *count = 0u;
    }
}

__global__ void k_edges(const int* __restrict__ ei, const int* __restrict__ sec,
                        unsigned* __restrict__ deg, unsigned* __restrict__ count,
                        int2* __restrict__ list) {
    int e = blockIdx.x * blockDim.x + threadIdx.x;
    if (e >= N_EDGES) return;
    int r = ei[e];             // message source
    int c = ei[N_EDGES + e];   // message target
    if (sec[r] == sec[c]) {
        atomicAdd(&deg[c], 1u);
        unsigned pos = atomicAdd(count, 1u);
        list[pos] = make_int2(r, c);
    }
}

// h = x @ W (bf16 MFMA, f32 accum); out = h/deg + b.
// 256 threads = 4 waves; wave w owns rows [blk*64 + w*16, +16), all 256 cols.
// A-fragments: f32 x loaded direct, converted in-register. B-fragments: 16B
// contiguous loads from L2-resident transposed Wt. No LDS, no barriers.
__global__ __launch_bounds__(256) void k_gemm(
        const float* __restrict__ x, const short* __restrict__ Wt,
        const float* __restrict__ b, const unsigned* __restrict__ deg,
        float* __restrict__ h, float* __restrict__ out) {
    const int lane = threadIdx.x & 63;
    const int wave = threadIdx.x >> 6;
    const int r16  = lane & 15;      // A row / B,C col within 16-tile
    const int kg   = lane >> 4;      // k-group (0..3)
    const int bm   = blockIdx.x * 64 + wave * 16;

    const float* xrow = x + (size_t)(bm + r16) * DIM + kg * 8;

    // prefetch the wave's entire A panel: 8 k-steps x 8 f32 per lane
    f32x4 xa[8][2];
    #pragma unroll
    for (int ks = 0; ks < 8; ++ks) {
        xa[ks][0] = *reinterpret_cast<const f32x4*>(xrow + ks * 32);
        xa[ks][1] = *reinterpret_cast<const f32x4*>(xrow + ks * 32 + 4);
    }

    f32x4 acc[16];
    #pragma unroll
    for (int i = 0; i < 16; ++i) acc[i] = (f32x4)0.f;

    const short* wp = Wt + (size_t)r16 * DIM + kg * 8;

    #pragma unroll
    for (int ks = 0; ks < 8; ++ks) {
        bf16x8 a;
        #pragma unroll
        for (int j = 0; j < 4; ++j) {
            a[j]     = f2bf(xa[ks][0][j]);
            a[4 + j] = f2bf(xa[ks][1][j]);
        }
        #pragma unroll
        for (int nf = 0; nf < 16; ++nf) {
            bf16x8 bv = *reinterpret_cast<const bf16x8*>(wp + (size_t)nf * 16 * DIM + ks * 32);
            acc[nf] = __builtin_amdgcn_mfma_f32_16x16x32_bf16(a, bv, acc[nf], 0, 0, 0);
        }
    }

    // epilogue: C/D layout col = lane&15, row = (lane>>4)*4 + r  [m89-verified]
    const int rbase = bm + kg * 4;
    uint4 dv = *reinterpret_cast<const uint4*>(deg + rbase);
    float inv[4] = {1.f / (float)dv.x, 1.f / (float)dv.y,
                    1.f / (float)dv.z, 1.f / (float)dv.w};
    #pragma unroll
    for (int nf = 0; nf < 16; ++nf) {
        int n = nf * 16 + r16;
        float bn = b[n];
        #pragma unroll
        for (int r = 0; r < 4; ++r) {
            float hv = acc[nf][r];
            h[(size_t)(rbase + r) * DIM + n]   = hv;
            out[(size_t)(rbase + r) * DIM + n] = hv * inv[r] + bn;
        }
    }
}

// one wave per active edge; lane l handles dims [4l, 4l+4)
__global__ void k_scatter(const float* __restrict__ h, const unsigned* __restrict__ deg,
                          const unsigned* __restrict__ count, const int2* __restrict__ list,
                          float* __restrict__ out) {
    unsigned nact = *count;
    unsigned wv     = (blockIdx.x * blockDim.x + threadIdx.x) >> 6;
    unsigned lane   = threadIdx.x & 63;
    unsigned nwaves = (gridDim.x * blockDim.x) >> 6;
    for (unsigned e = wv; e < nact; e += nwaves) {
        int2 rc = list[e];
        float norm = rsqrtf((float)deg[rc.x]) * rsqrtf((float)deg[rc.y]);
        float4 hv = *reinterpret_cast<const float4*>(&h[(size_t)rc.x * DIM + lane * 4]);
        float* o = &out[(size_t)rc.y * DIM + lane * 4];
        atomicAdd(o + 0, hv.x * norm);
        atomicAdd(o + 1, hv.y * norm);
        atomicAdd(o + 2, hv.z * norm);
        atomicAdd(o + 3, hv.w * norm);
    }
}

extern "C" void kernel_launch(void* const* d_in, const int* in_sizes, int n_in,
                              void* d_out, int out_size, void* d_ws, size_t ws_size,
                              hipStream_t stream) {
    const float* x  = (const float*)d_in[0];
    const float* W  = (const float*)d_in[1];
    const float* b  = (const float*)d_in[2];
    const int* ei   = (const int*)d_in[3];
    const int* sec  = (const int*)d_in[4];
    float* out      = (float*)d_out;

    char* ws = (char*)d_ws;
    unsigned* deg   = (unsigned*)ws;                       // 64 KB
    unsigned* count = (unsigned*)(ws + 65536);
    int2* list      = (int2*)(ws + 65536 + 256);
    size_t wt_off = 65536 + 256 + (size_t)N_EDGES * sizeof(int2);
    wt_off = (wt_off + 255) & ~(size_t)255;
    short* Wt = (short*)(ws + wt_off);
    size_t h_off = wt_off + (size_t)DIM * DIM * sizeof(short);
    h_off = (h_off + 255) & ~(size_t)255;
    float* h = (float*)(ws + h_off);

    k_prep<<<320, 256, 0, stream>>>(W, Wt, deg, count);
    k_edges<<<N_EDGES / 256, 256, 0, stream>>>(ei, sec, deg, count, list);
    k_gemm<<<N_NODES / 64, 256, 0, stream>>>(x, Wt, b, deg, h, out);
    k_scatter<<<256, 256, 0, stream>>>(h, deg, count, list, out);
}